// Round 8
// baseline (370.017 us; speedup 1.0000x reference)
//
#include <hip/hip_runtime.h>
#include <hip/hip_bf16.h>
#include <math.h>

typedef __bf16 bf16;
typedef __bf16 bf16x8 __attribute__((ext_vector_type(8)));
typedef __bf16 bf16x4 __attribute__((ext_vector_type(4)));
typedef float  f32x4  __attribute__((ext_vector_type(4)));

#define D_MODEL 384
#define HID     1536
#define NSEQ    1024
#define ROWS    16384
#define HEADS   8
#define DH      48
#define SCALE   0.14433756729740643f // 48^-0.5
#define BTAB_N  3969                 // 63*63
#define BTAB_PB 3976                 // bf16 elems, padded to 16B multiple
// packed KV tile geometry: [64 rows][72 cols] bf16 = 9216 B per tile
#define KVT     4608                 // elems per tile
#define QP_BH   (NSEQ * DH)          // 49152 elems per bh in Qpack
#define KP_BH   (16 * KVT)           // 73728 elems per bh in K/Vpack

__device__ __forceinline__ void gload16(const void* g, void* l) {
    __builtin_amdgcn_global_load_lds((const __attribute__((address_space(1))) void*)g,
                                     (__attribute__((address_space(3))) void*)l, 16, 0, 0);
}

// tanh-form GELU: max |err| vs exact erf-GELU ~1e-3 (below bf16 quantization)
__device__ __forceinline__ float fast_gelu(float x) {
    float u = 0.7978845608f * fmaf(0.044715f * x * x, x, x);
    float e = __expf(2.f * u);
    float t = 1.f - 2.f * __builtin_amdgcn_rcpf(e + 1.f);   // tanh(u)
    return 0.5f * x * (1.f + t);
}

// ---------------------------------------------------------------------------
// Bias prep: Btab[h][idx(dy,dx)] = (bf16)bias_table[ceil(dist)][h]
// (no MFIX: with a tile-invariant shift the softmax ratio is shift-independent)
// ---------------------------------------------------------------------------
__global__ __launch_bounds__(256)
void bias_prep_kernel(const float* __restrict__ bias_table, bf16* __restrict__ Btab)
{
    int idx = blockIdx.x * 256 + threadIdx.x;
    if (idx >= BTAB_N) return;
    int dy = idx / 63 - 31, dx = idx % 63 - 31;
    int s2 = dy * dy + dx * dx;
    int r = (int)ceilf(sqrtf((float)s2));
    while (r * r < s2) ++r;
    while (r > 0 && (r - 1) * (r - 1) >= s2) --r;
#pragma unroll
    for (int h = 0; h < HEADS; ++h)
        Btab[h * BTAB_PB + idx] = (bf16)bias_table[r * HEADS + h];
}

// ---------------------------------------------------------------------------
// Pack init (each launch; ws re-poisoned): zero Kpack pad cols 48..71,
// ones in Vpack rows 48..63 (the l-sum rows).
// ---------------------------------------------------------------------------
__global__ __launch_bounds__(256)
void pack_init_kernel(bf16* __restrict__ Kp, bf16* __restrict__ Vp)
{
    const int bid = blockIdx.x, tid = threadIdx.x;
    if (bid < 512) {                       // 131072 K-rows, pad cols 48..71
        int row = bid * 256 + tid;
        bf16x8 z = {};
        bf16* p = Kp + (size_t)row * 72 + 48;
        *(bf16x8*)(p) = z;  *(bf16x8*)(p + 8) = z;  *(bf16x8*)(p + 16) = z;
    } else {                               // 32768 V ones-rows
        int idx = (bid - 512) * 256 + tid;
        int tile = idx >> 4, rr = idx & 15;
        bf16 o = (bf16)1.f;
        bf16x8 ones = {o, o, o, o, o, o, o, o};
        bf16* p = Vp + (size_t)tile * KVT + (48 + rr) * 72;
#pragma unroll
        for (int c = 0; c < 9; ++c) *(bf16x8*)(p + c * 8) = ones;
    }
}

// ---------------------------------------------------------------------------
// Weight prep: out[n][k] = (bf16)in[k][n].
// ---------------------------------------------------------------------------
__global__ __launch_bounds__(256)
void wtrans_kernel(const float* __restrict__ in, bf16* __restrict__ out, int K, int N)
{
    __shared__ float T[64][65];
    const int k0 = blockIdx.y * 64, n0 = blockIdx.x * 64;
    const int rr = threadIdx.x >> 4, rc = threadIdx.x & 15;
#pragma unroll
    for (int i = 0; i < 4; ++i) {
        float4 v = *(const float4*)(in + (size_t)(k0 + rr + i * 16) * N + n0 + rc * 4);
        T[rr + i * 16][rc * 4 + 0] = v.x;  T[rr + i * 16][rc * 4 + 1] = v.y;
        T[rr + i * 16][rc * 4 + 2] = v.z;  T[rr + i * 16][rc * 4 + 3] = v.w;
    }
    __syncthreads();
#pragma unroll
    for (int i = 0; i < 4; ++i) {
        int n = rr + i * 16, kc = rc * 4;
        bf16x4 o;
        o[0] = (bf16)T[kc + 0][n];  o[1] = (bf16)T[kc + 1][n];
        o[2] = (bf16)T[kc + 2][n];  o[3] = (bf16)T[kc + 3][n];
        *(bf16x4*)(out + (size_t)(n0 + n) * K + k0 + kc) = o;
    }
}

// ---------------------------------------------------------------------------
// LayerNorm: one wave per row of 384. f32 in -> bf16 out.
// ---------------------------------------------------------------------------
__global__ __launch_bounds__(64)
void ln_kernel(const float* __restrict__ x, const float* __restrict__ w,
               const float* __restrict__ b, bf16* __restrict__ out)
{
    int row  = blockIdx.x;
    int lane = threadIdx.x;
    const float* xr = x + (size_t)row * D_MODEL;

    float v[6], s = 0.f, ss = 0.f;
#pragma unroll
    for (int i = 0; i < 6; ++i) {
        v[i] = xr[lane + i * 64];
        s  += v[i];
        ss += v[i] * v[i];
    }
#pragma unroll
    for (int off = 32; off; off >>= 1) {
        s  += __shfl_xor(s,  off);
        ss += __shfl_xor(ss, off);
    }
    float mu   = s * (1.f / D_MODEL);
    float var  = ss * (1.f / D_MODEL) - mu * mu;
    float rstd = rsqrtf(var + 1e-5f);

    bf16* orow = out + (size_t)row * D_MODEL;
#pragma unroll
    for (int i = 0; i < 6; ++i) {
        int c = lane + i * 64;
        orow[c] = (bf16)((v[i] - mu) * rstd * w[c] + b[c]);
    }
}

// ---------------------------------------------------------------------------
// GEMM: C[M,N] = A[M,K] @ BT[N,K]^T, bf16, 128x128 tile, BK=64, XCD swizzle.
// EPI 1: +bias +f32 res -> f32.  EPI 2: +bias, fast GELU -> bf16.
// EPI 3: packed Q/K/V stores via LDS round-trip (coalesced 16B stores).
// ---------------------------------------------------------------------------
template<int EPI, typename CT>
__global__ __launch_bounds__(256)
void gemm3_kernel(const bf16* __restrict__ A, const bf16* __restrict__ BT,
                  CT* __restrict__ C, const float* __restrict__ bias,
                  const float* __restrict__ res, int nxblk, int Nn, int K,
                  bf16* __restrict__ qp, bf16* __restrict__ kp, bf16* __restrict__ vp)
{
    constexpr int SMEM = (EPI == 3) ? (128 * 136 * 2) : 32768;   // Ts vs As+Bs
    __shared__ alignas(16) char smem[SMEM];
    bf16 (*As)[64] = (bf16(*)[64])smem;
    bf16 (*Bs)[64] = (bf16(*)[64])(smem + 16384);

    const int bid  = blockIdx.x;
    const int xcd  = bid & 7;
    const int slot = bid >> 3;
    const int yy   = slot / nxblk;
    const int m0   = (yy * 8 + xcd) * 128;
    const int n0   = (slot - yy * nxblk) * 128;

    const int tid  = threadIdx.x;
    const int w    = tid >> 6;
    const int lane = tid & 63;
    const int quad = lane >> 4;
    const int l16  = lane & 15;

    const int srow = lane >> 3;          // 0..7
    const int scol = (lane & 7) * 8;     // 0..56

    f32x4 acc[4][4] = {};

    for (int kt = 0; kt < K; kt += 64) {
        __syncthreads();
#pragma unroll
        for (int c = 0; c < 4; ++c) {
            const int ch = w * 4 + c;
            gload16(A  + (size_t)(m0 + ch * 8 + srow) * K + kt + scol, &As[ch * 8][0]);
            gload16(BT + (size_t)(n0 + ch * 8 + srow) * K + kt + scol, &Bs[ch * 8][0]);
        }
        __syncthreads();

#pragma unroll
        for (int kk = 0; kk < 2; ++kk) {
            bf16x8 af[4], bfr[4];
#pragma unroll
            for (int mt = 0; mt < 4; ++mt)
                af[mt] = *(const bf16x8*)(&As[(w & 1) * 64 + mt * 16 + l16][kk * 32 + quad * 8]);
#pragma unroll
            for (int nt = 0; nt < 4; ++nt)
                bfr[nt] = *(const bf16x8*)(&Bs[(w >> 1) * 64 + nt * 16 + l16][kk * 32 + quad * 8]);
#pragma unroll
            for (int mt = 0; mt < 4; ++mt)
#pragma unroll
                for (int nt = 0; nt < 4; ++nt)
                    acc[mt][nt] = __builtin_amdgcn_mfma_f32_16x16x32_bf16(
                        af[mt], bfr[nt], acc[mt][nt], 0, 0, 0);
        }
    }

    if (EPI != 3) {
#pragma unroll
        for (int mt = 0; mt < 4; ++mt) {
#pragma unroll
            for (int nt = 0; nt < 4; ++nt) {
                int c = n0 + (w >> 1) * 64 + nt * 16 + l16;
                float bi = bias ? bias[c] : 0.f;
#pragma unroll
                for (int r = 0; r < 4; ++r) {
                    int row = m0 + (w & 1) * 64 + mt * 16 + quad * 4 + r;
                    float v = acc[mt][nt][r] + bi;
                    if (EPI == 1) v += res[(size_t)row * Nn + c];
                    if (EPI == 2) v = fast_gelu(v);
                    C[(size_t)row * Nn + c] = (CT)v;
                }
            }
        }
    } else {
        // ---- packed QKV epilogue: acc -> Ts (LDS) -> coalesced 16B stores ----
        bf16 (*Ts)[136] = (bf16(*)[136])smem;
        const float mult = (n0 < 384) ? SCALE : 1.f;
        __syncthreads();   // done with As/Bs
#pragma unroll
        for (int mt = 0; mt < 4; ++mt)
#pragma unroll
            for (int nt = 0; nt < 4; ++nt)
#pragma unroll
                for (int r = 0; r < 4; ++r)
                    Ts[(w & 1) * 64 + mt * 16 + quad * 4 + r]
                      [(w >> 1) * 64 + nt * 16 + l16] = (bf16)(acc[mt][nt][r] * mult);
        __syncthreads();

        const int b = m0 >> 10, seqbase = m0 & 1023;
        if (n0 < 768) {
            // Q or K: tasks = (local row 0..127) x (8-col chunk 0..15)
            const bool isQ = (n0 < 384);
#pragma unroll
            for (int it = 0; it < 8; ++it) {
                int task = it * 256 + tid;
                int sq = task >> 4, ch = task & 15;
                int c0 = n0 + ch * 8 - (isQ ? 0 : 384);
                int h = c0 / 48, d0 = c0 - h * 48;
                bf16x8 v = *(const bf16x8*)(&Ts[sq][ch * 8]);
                int seq = seqbase + sq;
                if (isQ)
                    *(bf16x8*)(qp + (size_t)(b * 8 + h) * QP_BH + seq * 48 + d0) = v;
                else
                    *(bf16x8*)(kp + (size_t)(b * 8 + h) * KP_BH + (seq >> 6) * KVT
                               + (seq & 63) * 72 + d0) = v;
            }
        } else {
            // V transposed: tasks = (key chunk 0..15) x (local col 0..127)
#pragma unroll
            for (int it = 0; it < 8; ++it) {
                int task = it * 256 + tid;
                int colL = task & 127, kc = task >> 7;
                int key0 = kc * 8;
                int cv = n0 + colL - 768;
                int h = cv / 48, d = cv - h * 48;
                bf16x8 v;
#pragma unroll
                for (int j = 0; j < 8; ++j) v[j] = Ts[key0 + j][colL];
                int seq = seqbase + key0;
                *(bf16x8*)(vp + (size_t)(b * 8 + h) * KP_BH + (seq >> 6) * KVT
                           + d * 72 + (seq & 63)) = v;
            }
        }
    }
}

// ---------------------------------------------------------------------------
// MFMA flash attention v4: 128-query tile, single wave-private P buffer
// (strip-sequential), bf16 bias table, no softmax shift (ratio-invariant).
// LDS 35.6 KB -> 4 blocks/CU.
// ---------------------------------------------------------------------------
__global__ __launch_bounds__(256)
void attn_kernel(const bf16* __restrict__ Qp, const bf16* __restrict__ Kp,
                 const bf16* __restrict__ Vp, const bf16* __restrict__ Btab,
                 bf16* __restrict__ out)
{
    __shared__ alignas(16) bf16 Ks[64][72];     // [key][dh pad64; 48..63 zero]
    __shared__ alignas(16) bf16 Vs[64][72];     // [dh][key]; rows 48..63 ones
    __shared__ alignas(16) bf16 Ps[4][16][72];  // wave-private P: [query][key]
    __shared__ alignas(16) bf16 B2b[BTAB_PB];   // bias (bf16) for this head

    const int bid  = blockIdx.x;
    const int xcd  = bid & 7;
    const int slot = bid >> 3;
    const int qc   = slot & 7;
    const int bh   = (slot >> 3) * 8 + xcd;     // 0..127
    const int q0   = qc * 128;
    const int tid  = threadIdx.x;
    const int wave = tid >> 6;
    const int lane = tid & 63;
    const int quad = lane >> 4;
    const int l16  = lane & 15;
    const int b    = bh >> 3, h = bh & 7;

    // stage bias table (7952 B) via global_load_lds
    {
        const char* src = (const char*)(Btab + h * BTAB_PB);
#pragma unroll
        for (int it = 0; it < 2; ++it) {
            int off = it * 4096 + tid * 16;
            if (off < BTAB_PB * 2)
                gload16(src + off, (char*)B2b + it * 4096 + wave * 1024);
        }
    }

    // Q fragments for 2 strips (B-operand), SCALE pre-applied in Qpack
    bf16x8 qf0[2], qf1[2];
    int pi[2];
#pragma unroll
    for (int s = 0; s < 2; ++s) {
        int qrow = q0 + s * 64 + wave * 16 + l16;
        const bf16* qptr = Qp + (size_t)bh * QP_BH + qrow * 48;
        qf0[s] = *(const bf16x8*)(qptr + quad * 8);
#pragma unroll
        for (int c = 0; c < 8; ++c) qf1[s][c] = (bf16)0.f;
        if (quad < 2) qf1[s] = *(const bf16x8*)(qptr + 32 + quad * 8);
        pi[s] = (qrow >> 5) * 63 + (qrow & 31) + 31 * 63 + 31;
    }

    f32x4 o_acc[2][4] = {};   // [strip][0..2 = O dims, 3 = l]

    for (int t = 0; t < 16; ++t) {
        const int n0 = t * 64;
        const bf16* kbase = Kp + (size_t)(bh * 16 + t) * KVT;
        const bf16* vbase = Vp + (size_t)(bh * 16 + t) * KVT;
        __syncthreads();
        for (int i = wave; i < 9; i += 4) {
            gload16(kbase + i * 512 + lane * 8, (bf16*)Ks + i * 512);
            gload16(vbase + i * 512 + lane * 8, (bf16*)Vs + i * 512);
        }
        __syncthreads();

        // S^T = K @ Q^T: D[key=quad*4+r][query=l16], K-frags shared by strips
        f32x4 sa[2][4] = {};
#pragma unroll
        for (int nt = 0; nt < 4; ++nt) {
            bf16x8 a0 = *(const bf16x8*)(&Ks[nt * 16 + l16][quad * 8]);
            bf16x8 a1 = *(const bf16x8*)(&Ks[nt * 16 + l16][32 + quad * 8]);
#pragma unroll
            for (int s = 0; s < 2; ++s) {
                sa[s][nt] = __builtin_amdgcn_mfma_f32_16x16x32_bf16(a0, qf0[s], sa[s][nt], 0, 0, 0);
                sa[s][nt] = __builtin_amdgcn_mfma_f32_16x16x32_bf16(a1, qf1[s], sa[s][nt], 0, 0, 0);
            }
        }

        // strip-sequential: p = exp(s + bias) -> Ps (wave-private), then PV
#pragma unroll
        for (int s = 0; s < 2; ++s) {
#pragma unroll
            for (int nt = 0; nt < 4; ++nt) {
                const int j0 = n0 + nt * 16 + quad * 4;
                const int ib = pi[s] - ((j0 >> 5) * 63 + (j0 & 31));
                bf16x4 pk;
#pragma unroll
                for (int r = 0; r < 4; ++r)
                    pk[r] = (bf16)__expf(sa[s][nt][r] + (float)B2b[ib - r]);
                *(bf16x4*)(&Ps[wave][l16][nt * 16 + quad * 4]) = pk;
            }
#pragma unroll
            for (int kk = 0; kk < 2; ++kk) {
                bf16x8 pf = *(const bf16x8*)(&Ps[wave][l16][kk * 32 + quad * 8]);
#pragma unroll
                for (int d = 0; d < 4; ++d) {
                    bf16x8 vf = *(const bf16x8*)(&Vs[d * 16 + l16][kk * 32 + quad * 8]);
                    o_acc[s][d] = __builtin_amdgcn_mfma_f32_16x16x32_bf16(
                        pf, vf, o_acc[s][d], 0, 0, 0);
                }
            }
        }
    }

    // epilogue
#pragma unroll
    for (int s = 0; s < 2; ++s)
#pragma unroll
        for (int r = 0; r < 4; ++r) {
            float inv = 1.f / o_acc[s][3][r];
            int row = q0 + s * 64 + wave * 16 + quad * 4 + r;
            bf16* orow = out + ((size_t)b * NSEQ + row) * D_MODEL + h * DH;
#pragma unroll
            for (int d = 0; d < 3; ++d)
                orow[d * 16 + l16] = (bf16)(o_acc[s][d][r] * inv);
        }
}

// ---------------------------------------------------------------------------
extern "C" void kernel_launch(void* const* d_in, const int* in_sizes, int n_in,
                              void* d_out, int out_size, void* d_ws, size_t ws_size,
                              hipStream_t stream)
{
    const float* x          = (const float*)d_in[0];
    const float* ln1_w      = (const float*)d_in[1];
    const float* ln1_b      = (const float*)d_in[2];
    const float* w_qkv      = (const float*)d_in[3];
    const float* bias_table = (const float*)d_in[4];
    const float* w_out      = (const float*)d_in[5];
    const float* b_out      = (const float*)d_in[6];
    const float* ln2_w      = (const float*)d_in[7];
    const float* ln2_b      = (const float*)d_in[8];
    const float* w1         = (const float*)d_in[9];
    const float* b1         = (const float*)d_in[10];
    const float* w2         = (const float*)d_in[11];
    const float* b2         = (const float*)d_in[12];
    float* out = (float*)d_out;

    bf16* regA  = (bf16*)d_ws;                    // 25.17M elems: packs, later gelu
    bf16* Qpack = regA;                           // [128][1024][48]     6.29M
    bf16* Kpack = regA + 6291456;                 // [128][16][64][72]   9.44M
    bf16* Vpack = regA + 15728640;                // [128][16][64][72]   9.44M
    bf16* regB  = regA + (size_t)ROWS * HID;      // [16384][384]
    bf16* wqkvT = regB + (size_t)ROWS * D_MODEL;  // [1152][384]
    bf16* woutT = wqkvT + 1152 * 384;             // [384][384]
    bf16* w1T   = woutT + 384 * 384;              // [1536][384]
    bf16* w2T   = w1T + 1536 * 384;               // [384][1536]
    bf16* Btab  = w2T + 384 * 1536;               // [8][3976] bf16
    float* x1   = out;                            // residual in d_out (f32)

    bias_prep_kernel<<<(BTAB_N + 255) / 256, 256, 0, stream>>>(bias_table, Btab);
    pack_init_kernel<<<640, 256, 0, stream>>>(Kpack, Vpack);
    wtrans_kernel<<<dim3(1152 / 64, 384 / 64), 256, 0, stream>>>(w_qkv, wqkvT, 384, 1152);
    wtrans_kernel<<<dim3(384 / 64, 384 / 64), 256, 0, stream>>>(w_out, woutT, 384, 384);
    wtrans_kernel<<<dim3(1536 / 64, 384 / 64), 256, 0, stream>>>(w1, w1T, 384, 1536);
    wtrans_kernel<<<dim3(384 / 64, 1536 / 64), 256, 0, stream>>>(w2, w2T, 1536, 384);

    // 1. LN1 -> regB
    ln_kernel<<<ROWS, 64, 0, stream>>>(x, ln1_w, ln1_b, regB);
    // 2. qkv GEMM -> packed Q/K/V (EPI3, LDS-coalesced stores)
    gemm3_kernel<3, bf16><<<(1152 / 128) * (ROWS / 128), 256, 0, stream>>>(
        regB, wqkvT, (bf16*)nullptr, nullptr, nullptr, 1152 / 128, 1152, D_MODEL,
        Qpack, Kpack, Vpack);
    // 3. attention -> regB
    attn_kernel<<<1024, 256, 0, stream>>>(Qpack, Kpack, Vpack, Btab, regB);
    // 4. x1 = attn @ w_out + b_out + x -> d_out (f32)
    gemm3_kernel<1, float><<<(D_MODEL / 128) * (ROWS / 128), 256, 0, stream>>>(
        regB, woutT, x1, b_out, x, D_MODEL / 128, D_MODEL, D_MODEL,
        nullptr, nullptr, nullptr);
    // 5. LN2 -> regB
    ln_kernel<<<ROWS, 64, 0, stream>>>(x1, ln2_w, ln2_b, regB);
    // 6. gelu(h2 @ w1 + b1) -> regA (packs dead now)
    gemm3_kernel<2, bf16><<<(HID / 128) * (ROWS / 128), 256, 0, stream>>>(
        regB, w1T, regA, b1, nullptr, HID / 128, HID, D_MODEL,
        nullptr, nullptr, nullptr);
    // 7. out = gelu @ w2 + b2 + x1
    gemm3_kernel<1, float><<<(D_MODEL / 128) * (ROWS / 128), 256, 0, stream>>>(
        regA, w2T, out, b2, x1, D_MODEL / 128, D_MODEL, HID,
        nullptr, nullptr, nullptr);
}